// Round 5
// baseline (261.855 us; speedup 1.0000x reference)
//
#include <hip/hip_runtime.h>
#include <hip/hip_bf16.h>

typedef __attribute__((ext_vector_type(8))) short short8;
typedef __attribute__((ext_vector_type(4))) short short4v;
typedef __attribute__((ext_vector_type(4))) unsigned short ushort4v;
typedef __attribute__((ext_vector_type(4))) float f32x4;

#define NTOK 8192
#define DM 1024
#define DE 1024
#define NE 8

__device__ __forceinline__ float bf2f(unsigned short u) {
  union { unsigned int i; float f; } v; v.i = ((unsigned int)u) << 16; return v.f;
}
__device__ __forceinline__ unsigned short f2bf(float f) {
  union { float f; unsigned int i; } v; v.f = f;
  unsigned int lsb = (v.i >> 16) & 1;
  v.i += 0x7fffu + lsb;  // RNE; inputs finite
  return (unsigned short)(v.i >> 16);
}
__device__ __forceinline__ void gl_lds(const short* g, short* l) {
  __builtin_amdgcn_global_load_lds((const __attribute__((address_space(1))) void*)g,
                                   (__attribute__((address_space(3))) void*)l, 16, 0, 0);
}

// ------- W fp32 [K][N] -> bf16 transposed; W1/W3 interleaved into wcat -------
// wcat[e]: 2048 rows in 256-row groups: group g rows [g*256, g*256+128) = W1^T
//          cols g*128+[0,128); rows +128 = W3^T same cols. (BN=256 tile = one
//          group = 128 matched W1/W3 column pairs.)
// w2t[e]: plain W2^T [1024][1024]
__global__ __launch_bounds__(256) void k_transw(const float* __restrict__ W1,
                                                const float* __restrict__ W2,
                                                const float* __restrict__ W3,
                                                short* __restrict__ wcat,
                                                short* __restrict__ w2t) {
  __shared__ float t[64][65];
  int mid = blockIdx.z;
  const float* src;
  if (mid < 8)       src = W1 + (size_t)mid * (DM * DE);
  else if (mid < 16) src = W3 + (size_t)(mid - 8) * (DM * DE);
  else               src = W2 + (size_t)(mid - 16) * (DE * DM);
  int tid = threadIdx.x;
  int tr = tid >> 4, tc = tid & 15;
  int kbase = blockIdx.y * 64, nbase = blockIdx.x * 64;
#pragma unroll
  for (int j = 0; j < 4; j++) {
    int kr = tr + j * 16;
    f32x4 v = *(const f32x4*)(src + (size_t)(kbase + kr) * 1024 + nbase + tc * 4);
    t[kr][tc * 4 + 0] = v[0]; t[kr][tc * 4 + 1] = v[1];
    t[kr][tc * 4 + 2] = v[2]; t[kr][tc * 4 + 3] = v[3];
  }
  __syncthreads();
#pragma unroll
  for (int j = 0; j < 4; j++) {
    int n = tr + j * 16;          // source column (0..1023 within this matrix)
    int ng = nbase + n;
    short4v o;
    o[0] = (short)f2bf(t[tc * 4 + 0][n]);
    o[1] = (short)f2bf(t[tc * 4 + 1][n]);
    o[2] = (short)f2bf(t[tc * 4 + 2][n]);
    o[3] = (short)f2bf(t[tc * 4 + 3][n]);
    size_t dsto;
    if (mid < 16) {
      int e = mid & 7, p = mid >> 3;
      int row_out = ((ng >> 7) * 256) + p * 128 + (ng & 127);
      dsto = (size_t)e * (2048 * 1024) + (size_t)row_out * 1024 + kbase + tc * 4;
      *(short4v*)(wcat + dsto) = o;
    } else {
      int e = mid - 16;
      dsto = (size_t)e * (1024 * 1024) + (size_t)ng * 1024 + kbase + tc * 4;
      *(short4v*)(w2t + dsto) = o;
    }
  }
}

// ------- router: fp32 logits, softmax-top2, fused x->bf16 conversion -------
__global__ __launch_bounds__(256) void k_router(const float* __restrict__ x,
                                                const float* __restrict__ Wr,
                                                short* __restrict__ xb,
                                                int* __restrict__ esel,
                                                float* __restrict__ wgt) {
  int wid = threadIdx.x >> 6, lane = threadIdx.x & 63;
  int t = blockIdx.x * 4 + wid;
  const float* xr = x + (size_t)t * DM;
  float acc[8];
#pragma unroll
  for (int e = 0; e < 8; e++) acc[e] = 0.f;
#pragma unroll
  for (int i = 0; i < 4; i++) {
    int kb = (i * 64 + lane) * 4;
    f32x4 v = *(const f32x4*)(xr + kb);
    ushort4v ob;
#pragma unroll
    for (int j = 0; j < 4; j++) {
      f32x4 w0 = *(const f32x4*)(Wr + (size_t)(kb + j) * 8);
      f32x4 w1 = *(const f32x4*)(Wr + (size_t)(kb + j) * 8 + 4);
      float xv = v[j];
      ob[j] = f2bf(xv);
      acc[0] += xv * w0[0]; acc[1] += xv * w0[1];
      acc[2] += xv * w0[2]; acc[3] += xv * w0[3];
      acc[4] += xv * w1[0]; acc[5] += xv * w1[1];
      acc[6] += xv * w1[2]; acc[7] += xv * w1[3];
    }
    *(ushort4v*)(xb + (size_t)t * DM + kb) = ob;
  }
#pragma unroll
  for (int off = 32; off; off >>= 1)
#pragma unroll
    for (int e = 0; e < 8; e++) acc[e] += __shfl_xor(acc[e], off);
  float m0 = -1e30f, m1 = -1e30f; int e0 = 0, e1 = 0;
#pragma unroll
  for (int e = 0; e < 8; e++) {
    float v = acc[e];
    if (v > m0) { m1 = m0; e1 = e0; m0 = v; e0 = e; }
    else if (v > m1) { m1 = v; e1 = e; }
  }
  float p = __expf(m1 - m0);
  if (lane == 0) {
    esel[2 * t] = e0; esel[2 * t + 1] = e1;
    wgt[2 * t] = 1.f / (1.f + p); wgt[2 * t + 1] = p / (1.f + p);
  }
}

// ---- ranks via wave ballots + per-block aggregated atomics ----
__global__ __launch_bounds__(256) void k_rank(const int* __restrict__ esel,
                                              int* __restrict__ cnt,
                                              int* __restrict__ rank) {
  __shared__ int wcnt[4][8];
  __shared__ int woff[4][8];
  int tid = threadIdx.x;
  int lane = tid & 63, wid = tid >> 6;
  int t = blockIdx.x * 256 + tid;
  int e0 = esel[2 * t], e1 = esel[2 * t + 1];
  unsigned long long lt = (lane == 0) ? 0ull : ((~0ull) >> (64 - lane));
  int r0 = 0, r1 = 0;
#pragma unroll
  for (int e = 0; e < 8; e++) {
    unsigned long long m0 = __ballot(e0 == e);
    unsigned long long m1 = __ballot(e1 == e);
    int c0 = __popcll(m0);
    if (e0 == e) r0 = __popcll(m0 & lt);
    if (e1 == e) r1 = c0 + __popcll(m1 & lt);
    if (lane == 0) wcnt[wid][e] = c0 + __popcll(m1);
  }
  __syncthreads();
  if (tid < 8) {
    int e = tid;
    int c0 = wcnt[0][e], c1 = wcnt[1][e], c2 = wcnt[2][e], c3 = wcnt[3][e];
    int base = atomicAdd(&cnt[e], c0 + c1 + c2 + c3);
    woff[0][e] = base;
    woff[1][e] = base + c0;
    woff[2][e] = base + c0 + c1;
    woff[3][e] = base + c0 + c1 + c2;
  }
  __syncthreads();
  rank[2 * t] = woff[wid][e0] + r0;
  rank[2 * t + 1] = woff[wid][e1] + r1;
}

__global__ void k_offsets(const int* __restrict__ cnt, int* __restrict__ off) {
  if (threadIdx.x == 0) {
    int s = 0;
    for (int e = 0; e < NE; e++) { off[e] = s; s += cnt[e]; }
  }
}

__global__ __launch_bounds__(256) void k_scatter(const int* __restrict__ off,
                                                 const int* __restrict__ esel,
                                                 const int* __restrict__ rank,
                                                 int* __restrict__ tok_of_slot,
                                                 int* __restrict__ slot_of_tok) {
  int t = blockIdx.x * 256 + threadIdx.x;
#pragma unroll
  for (int j = 0; j < 2; j++) {
    int e = esel[2 * t + j];
    int s = off[e] + rank[2 * t + j];
    tok_of_slot[s] = t;
    slot_of_tok[2 * t + j] = s;
  }
}

// ========= 256x256-tile BK=64 grouped GEMM, 8-phase-style, dbuf 128KB =========
// m201-port: 1 block/CU, 8 waves = 2(M:wr) x 4(N:wcn), wave tile 128x64,
// acc[8][4] f32x4 = 128 AGPR (launch_bounds(512,2) -> 2 waves/SIMD, <=256 regs).
// LDS: A[2][256][64] + B[2][256][64] bf16 = 128 KB. Row = 128B = full bank
// wrap; swizzle: 16B-chunk c stored at c ^ (row&7)  (64 lanes spread 8 per
// chunk = minimum aliasing for ds_read_b128 -> conflict-free). Staged with
// linear LDS dest + inverse-swizzled global source (both-sides involution).
// Per K-tile (BK=64): 4 phases x {ds_read 4-8 frags, MFMA 16}; A-stage of
// tile t+1 issued in phase 0, B-stage in phase 1 -> single vmcnt(0)+barrier
// gate per tile lands ~3 phases after issue (latency covered). 64 MFMA/wave
// between barriers.
// FFN1=1: A = xb gathered via tok_of_slot, B = wcat group (128 W1 + 128 W3
//         col pairs; n-frags (0,1)=W1, (2,3)=W3 same cols -> silu lane-local),
//         epilogue silu(a1)*a3 -> h (128 cols/blk)
// FFN1=0: A = h (slot rows), B = w2t, epilogue -> y (256 cols/blk)
template<int FFN1>
__global__ __launch_bounds__(512, 2) void k_ffn(const short* __restrict__ Abase,
                                                const short* __restrict__ Bbase,
                                                const int* __restrict__ cnt,
                                                const int* __restrict__ off,
                                                const int* __restrict__ tok_of_slot,
                                                short* __restrict__ outp) {
  const int e = blockIdx.y;
  const int cnt_e = cnt[e];
  const int m0 = blockIdx.z * 256;
  if (m0 >= cnt_e) return;
  const int bse = off[e];
  const int nt = blockIdx.x;
  const short* Bt = Bbase + (size_t)e * ((FFN1 ? 2048 : 1024) * 1024) + (size_t)(nt * 256) * 1024;

  __shared__ __align__(128) short Al[2][16384];  // [256][64] x2 = 64 KB
  __shared__ __align__(128) short Bl[2][16384];  // 64 KB (128 KB total)

  const int tid = threadIdx.x;
  const int lane = tid & 63, wid = tid >> 6;
  const int wr = wid >> 2, wcn = wid & 3;

  // staging: piece p (4 per matrix): row r = p*64 + tid/8; lds chunk = tid&7;
  // source chunk sc = (tid&7) ^ (r&7)  (inverse swizzle; LDS dest linear)
  const short* srcA[4]; const short* srcB[4];
#pragma unroll
  for (int p = 0; p < 4; p++) {
    int r = p * 64 + (tid >> 3);
    int sc = (tid & 7) ^ (r & 7);
    int rowA = m0 + r; if (rowA >= cnt_e) rowA = cnt_e - 1;
    long ar = FFN1 ? (long)tok_of_slot[bse + rowA] : (long)(bse + rowA);
    srcA[p] = Abase + ar * 1024 + sc * 8;
    srcB[p] = Bt + (size_t)r * 1024 + sc * 8;
  }

  // fragment LDS byte offsets (ks=0); ks=1 offset = ks0 ^ 64 (chunk ^= 4)
  int aoff[8], boff[4];
#pragma unroll
  for (int m = 0; m < 8; m++) {
    int r = wr * 128 + m * 16 + (lane & 15);
    aoff[m] = r * 128 + (((lane >> 4) ^ (r & 7)) * 16);
  }
#pragma unroll
  for (int n = 0; n < 4; n++) {
    int rb = FFN1 ? (wcn * 32 + (n & 1) * 16 + (n >> 1) * 128 + (lane & 15))
                  : (wcn * 64 + n * 16 + (lane & 15));
    boff[n] = rb * 128 + (((lane >> 4) ^ (rb & 7)) * 16);
  }

  f32x4 acc[8][4];
#pragma unroll
  for (int m = 0; m < 8; m++)
#pragma unroll
    for (int n = 0; n < 4; n++) acc[m][n] = (f32x4){0.f, 0.f, 0.f, 0.f};

  // prologue: stage tile 0 into buf 0
#pragma unroll
  for (int p = 0; p < 4; p++) gl_lds(srcA[p], &Al[0][p * 4096 + wid * 512]);
#pragma unroll
  for (int p = 0; p < 4; p++) gl_lds(srcB[p], &Bl[0][p * 4096 + wid * 512]);
  asm volatile("s_waitcnt vmcnt(0)" ::: "memory");
  __builtin_amdgcn_s_barrier();

  int cur = 0;
  for (int t = 0; t < 16; ++t) {
    const int nxt = cur ^ 1;
    const int ktn = (t + 1 < 16) ? (t + 1) : 15;  // clamped dup-stage, benign
    const char* Ab = (const char*)Al[cur];
    const char* Bb = (const char*)Bl[cur];
    short8 a[4], b[4];
    // ---- phase 0: ks0/mh0 frags + all B(ks0); issue next A-stage ----
#pragma unroll
    for (int i = 0; i < 4; i++) a[i] = *(const short8*)(Ab + aoff[i]);
#pragma unroll
    for (int i = 0; i < 4; i++) b[i] = *(const short8*)(Bb + boff[i]);
#pragma unroll
    for (int p = 0; p < 4; p++) gl_lds(srcA[p] + ktn * 64, &Al[nxt][p * 4096 + wid * 512]);
    __builtin_amdgcn_s_setprio(1);
#pragma unroll
    for (int m = 0; m < 4; m++)
#pragma unroll
      for (int n = 0; n < 4; n++)
        acc[m][n] = __builtin_amdgcn_mfma_f32_16x16x32_bf16(a[m], b[n], acc[m][n], 0, 0, 0);
    // ---- phase 1: ks0/mh1; issue next B-stage ----
#pragma unroll
    for (int i = 0; i < 4; i++) a[i] = *(const short8*)(Ab + aoff[4 + i]);
#pragma unroll
    for (int p = 0; p < 4; p++) gl_lds(srcB[p] + ktn * 64, &Bl[nxt][p * 4096 + wid * 512]);
#pragma unroll
    for (int m = 0; m < 4; m++)
#pragma unroll
      for (int n = 0; n < 4; n++)
        acc[m + 4][n] = __builtin_amdgcn_mfma_f32_16x16x32_bf16(a[m], b[n], acc[m + 4][n], 0, 0, 0);
    // ---- phase 2: ks1/mh0 ----
#pragma unroll
    for (int i = 0; i < 4; i++) a[i] = *(const short8*)(Ab + (aoff[i] ^ 64));
#pragma unroll
    for (int i = 0; i < 4; i++) b[i] = *(const short8*)(Bb + (boff[i] ^ 64));
#pragma unroll
    for (int m = 0; m < 4; m++)
#pragma unroll
      for (int n = 0; n < 4; n++)
        acc[m][n] = __builtin_amdgcn_mfma_f32_16x16x32_bf16(a[m], b[n], acc[m][n], 0, 0, 0);
    // ---- phase 3: ks1/mh1 ----
#pragma unroll
    for (int i = 0; i < 4; i++) a[i] = *(const short8*)(Ab + (aoff[4 + i] ^ 64));
#pragma unroll
    for (int m = 0; m < 4; m++)
#pragma unroll
      for (int n = 0; n < 4; n++)
        acc[m + 4][n] = __builtin_amdgcn_mfma_f32_16x16x32_bf16(a[m], b[n], acc[m + 4][n], 0, 0, 0);
    __builtin_amdgcn_s_setprio(0);
    asm volatile("s_waitcnt vmcnt(0)" ::: "memory");  // next tile landed
    __builtin_amdgcn_s_barrier();
    cur = nxt;
  }

  // ---- epilogue ----
  if (FFN1) {
#pragma unroll
    for (int m = 0; m < 8; m++)
#pragma unroll
      for (int cc = 0; cc < 2; cc++) {
        f32x4 v1 = acc[m][cc], v3 = acc[m][cc + 2];
        int col = nt * 128 + wcn * 32 + cc * 16 + (lane & 15);
#pragma unroll
        for (int i = 0; i < 4; i++) {
          int row = m0 + wr * 128 + m * 16 + ((lane >> 4) * 4) + i;
          if (row < cnt_e) {
            float a1v = v1[i];
            float hv = (a1v / (1.f + __expf(-a1v))) * v3[i];
            outp[(size_t)(bse + row) * DE + col] = (short)f2bf(hv);
          }
        }
      }
  } else {
#pragma unroll
    for (int m = 0; m < 8; m++)
#pragma unroll
      for (int n = 0; n < 4; n++) {
        f32x4 v = acc[m][n];
        int col = nt * 256 + wcn * 64 + n * 16 + (lane & 15);
#pragma unroll
        for (int i = 0; i < 4; i++) {
          int row = m0 + wr * 128 + m * 16 + ((lane >> 4) * 4) + i;
          if (row < cnt_e)
            outp[(size_t)(bse + row) * DM + col] = (short)f2bf(v[i]);
        }
      }
  }
}

// ---------------- combine: out[t] = w0*y[s0] + w1*y[s1] ----------------
__global__ __launch_bounds__(256) void k_combine(const short* __restrict__ y,
                                                 const int* __restrict__ slot_of_tok,
                                                 const float* __restrict__ wgt,
                                                 float* __restrict__ out) {
  int t = blockIdx.x;
  int s0 = slot_of_tok[2 * t], s1 = slot_of_tok[2 * t + 1];
  float w0 = wgt[2 * t], w1 = wgt[2 * t + 1];
  int c = threadIdx.x * 4;
  short4v a = *(const short4v*)(y + (size_t)s0 * DM + c);
  short4v b = *(const short4v*)(y + (size_t)s1 * DM + c);
  f32x4 o;
#pragma unroll
  for (int j = 0; j < 4; j++)
    o[j] = w0 * bf2f((unsigned short)a[j]) + w1 * bf2f((unsigned short)b[j]);
  *(f32x4*)(out + (size_t)t * DM + c) = o;
}

extern "C" void kernel_launch(void* const* d_in, const int* in_sizes, int n_in,
                              void* d_out, int out_size, void* d_ws, size_t ws_size,
                              hipStream_t stream) {
  const float* x  = (const float*)d_in[0];
  const float* Wr = (const float*)d_in[1];
  const float* W1 = (const float*)d_in[2];
  const float* W2 = (const float*)d_in[3];
  const float* W3 = (const float*)d_in[4];
  float* out = (float*)d_out;
  char* ws = (char*)d_ws;

  short* xb   = (short*)(ws);                   // 16 MB
  short* wcat = (short*)(ws + 16777216);        // 32 MB (8 x 2048 x 1024 bf16)
  short* w2t  = (short*)(ws + 50331648);        // 16 MB
  short* h    = (short*)(ws + 67108864);        // 32 MB
  short* y    = (short*)(ws + 100663296);       // 32 MB
  char* meta = ws + 134217728;
  int* cnt          = (int*)(meta);
  int* off          = (int*)(meta + 256);
  int* esel         = (int*)(meta + 512);
  int* rank         = (int*)(meta + 512 + 65536);
  int* tok_of_slot  = (int*)(meta + 512 + 2 * 65536);
  int* slot_of_tok  = (int*)(meta + 512 + 3 * 65536);
  float* wgt        = (float*)(meta + 512 + 4 * 65536);

  hipMemsetAsync(cnt, 0, 32, stream);
  k_transw<<<dim3(16, 16, 24), 256, 0, stream>>>(W1, W2, W3, wcat, w2t);
  k_router<<<2048, 256, 0, stream>>>(x, Wr, xb, esel, wgt);
  k_rank<<<32, 256, 0, stream>>>(esel, cnt, rank);
  k_offsets<<<1, 64, 0, stream>>>(cnt, off);
  k_scatter<<<32, 256, 0, stream>>>(off, esel, rank, tok_of_slot, slot_of_tok);
  k_ffn<1><<<dim3(8, 8, 32), 512, 0, stream>>>(xb, wcat, cnt, off, tok_of_slot, h);
  k_ffn<0><<<dim3(4, 8, 32), 512, 0, stream>>>(h, w2t, cnt, off, tok_of_slot, y);
  k_combine<<<8192, 256, 0, stream>>>(y, slot_of_tok, wgt, out);
}

// Round 6
// 253.670 us; speedup vs baseline: 1.0323x; 1.0323x over previous
//
#include <hip/hip_runtime.h>
#include <hip/hip_bf16.h>

typedef __attribute__((ext_vector_type(8))) short short8;
typedef __attribute__((ext_vector_type(4))) short short4v;
typedef __attribute__((ext_vector_type(4))) unsigned short ushort4v;
typedef __attribute__((ext_vector_type(4))) float f32x4;

#define NTOK 8192
#define DM 1024
#define DE 1024
#define NE 8

__device__ __forceinline__ float bf2f(unsigned short u) {
  union { unsigned int i; float f; } v; v.i = ((unsigned int)u) << 16; return v.f;
}
__device__ __forceinline__ unsigned short f2bf(float f) {
  union { float f; unsigned int i; } v; v.f = f;
  unsigned int lsb = (v.i >> 16) & 1;
  v.i += 0x7fffu + lsb;  // RNE; inputs finite
  return (unsigned short)(v.i >> 16);
}
__device__ __forceinline__ void gl_lds(const short* g, short* l) {
  __builtin_amdgcn_global_load_lds((const __attribute__((address_space(1))) void*)g,
                                   (__attribute__((address_space(3))) void*)l, 16, 0, 0);
}

// ------- W fp32 [K][N] -> bf16 transposed; W1/W3 interleaved into wcat -------
// wcat[e]: 2048 rows in 256-row groups: group g rows [g*256, g*256+128) = W1^T
//          cols g*128+[0,128); rows +128 = W3^T same cols. (BN=256 tile = one
//          group = 128 matched W1/W3 column pairs.)
// w2t[e]: plain W2^T [1024][1024]
__global__ __launch_bounds__(256) void k_transw(const float* __restrict__ W1,
                                                const float* __restrict__ W2,
                                                const float* __restrict__ W3,
                                                short* __restrict__ wcat,
                                                short* __restrict__ w2t) {
  __shared__ float t[64][65];
  int mid = blockIdx.z;
  const float* src;
  if (mid < 8)       src = W1 + (size_t)mid * (DM * DE);
  else if (mid < 16) src = W3 + (size_t)(mid - 8) * (DM * DE);
  else               src = W2 + (size_t)(mid - 16) * (DE * DM);
  int tid = threadIdx.x;
  int tr = tid >> 4, tc = tid & 15;
  int kbase = blockIdx.y * 64, nbase = blockIdx.x * 64;
#pragma unroll
  for (int j = 0; j < 4; j++) {
    int kr = tr + j * 16;
    f32x4 v = *(const f32x4*)(src + (size_t)(kbase + kr) * 1024 + nbase + tc * 4);
    t[kr][tc * 4 + 0] = v[0]; t[kr][tc * 4 + 1] = v[1];
    t[kr][tc * 4 + 2] = v[2]; t[kr][tc * 4 + 3] = v[3];
  }
  __syncthreads();
#pragma unroll
  for (int j = 0; j < 4; j++) {
    int n = tr + j * 16;          // source column (0..1023 within this matrix)
    int ng = nbase + n;
    short4v o;
    o[0] = (short)f2bf(t[tc * 4 + 0][n]);
    o[1] = (short)f2bf(t[tc * 4 + 1][n]);
    o[2] = (short)f2bf(t[tc * 4 + 2][n]);
    o[3] = (short)f2bf(t[tc * 4 + 3][n]);
    size_t dsto;
    if (mid < 16) {
      int e = mid & 7, p = mid >> 3;
      int row_out = ((ng >> 7) * 256) + p * 128 + (ng & 127);
      dsto = (size_t)e * (2048 * 1024) + (size_t)row_out * 1024 + kbase + tc * 4;
      *(short4v*)(wcat + dsto) = o;
    } else {
      int e = mid - 16;
      dsto = (size_t)e * (1024 * 1024) + (size_t)ng * 1024 + kbase + tc * 4;
      *(short4v*)(w2t + dsto) = o;
    }
  }
}

// ------- router: fp32 logits, softmax-top2, fused x->bf16 conversion -------
__global__ __launch_bounds__(256) void k_router(const float* __restrict__ x,
                                                const float* __restrict__ Wr,
                                                short* __restrict__ xb,
                                                int* __restrict__ esel,
                                                float* __restrict__ wgt) {
  int wid = threadIdx.x >> 6, lane = threadIdx.x & 63;
  int t = blockIdx.x * 4 + wid;
  const float* xr = x + (size_t)t * DM;
  float acc[8];
#pragma unroll
  for (int e = 0; e < 8; e++) acc[e] = 0.f;
#pragma unroll
  for (int i = 0; i < 4; i++) {
    int kb = (i * 64 + lane) * 4;
    f32x4 v = *(const f32x4*)(xr + kb);
    ushort4v ob;
#pragma unroll
    for (int j = 0; j < 4; j++) {
      f32x4 w0 = *(const f32x4*)(Wr + (size_t)(kb + j) * 8);
      f32x4 w1 = *(const f32x4*)(Wr + (size_t)(kb + j) * 8 + 4);
      float xv = v[j];
      ob[j] = f2bf(xv);
      acc[0] += xv * w0[0]; acc[1] += xv * w0[1];
      acc[2] += xv * w0[2]; acc[3] += xv * w0[3];
      acc[4] += xv * w1[0]; acc[5] += xv * w1[1];
      acc[6] += xv * w1[2]; acc[7] += xv * w1[3];
    }
    *(ushort4v*)(xb + (size_t)t * DM + kb) = ob;
  }
#pragma unroll
  for (int off = 32; off; off >>= 1)
#pragma unroll
    for (int e = 0; e < 8; e++) acc[e] += __shfl_xor(acc[e], off);
  float m0 = -1e30f, m1 = -1e30f; int e0 = 0, e1 = 0;
#pragma unroll
  for (int e = 0; e < 8; e++) {
    float v = acc[e];
    if (v > m0) { m1 = m0; e1 = e0; m0 = v; e0 = e; }
    else if (v > m1) { m1 = v; e1 = e; }
  }
  float p = __expf(m1 - m0);
  if (lane == 0) {
    esel[2 * t] = e0; esel[2 * t + 1] = e1;
    wgt[2 * t] = 1.f / (1.f + p); wgt[2 * t + 1] = p / (1.f + p);
  }
}

// ---- ranks via wave ballots + per-block aggregated atomics ----
__global__ __launch_bounds__(256) void k_rank(const int* __restrict__ esel,
                                              int* __restrict__ cnt,
                                              int* __restrict__ rank) {
  __shared__ int wcnt[4][8];
  __shared__ int woff[4][8];
  int tid = threadIdx.x;
  int lane = tid & 63, wid = tid >> 6;
  int t = blockIdx.x * 256 + tid;
  int e0 = esel[2 * t], e1 = esel[2 * t + 1];
  unsigned long long lt = (lane == 0) ? 0ull : ((~0ull) >> (64 - lane));
  int r0 = 0, r1 = 0;
#pragma unroll
  for (int e = 0; e < 8; e++) {
    unsigned long long m0 = __ballot(e0 == e);
    unsigned long long m1 = __ballot(e1 == e);
    int c0 = __popcll(m0);
    if (e0 == e) r0 = __popcll(m0 & lt);
    if (e1 == e) r1 = c0 + __popcll(m1 & lt);
    if (lane == 0) wcnt[wid][e] = c0 + __popcll(m1);
  }
  __syncthreads();
  if (tid < 8) {
    int e = tid;
    int c0 = wcnt[0][e], c1 = wcnt[1][e], c2 = wcnt[2][e], c3 = wcnt[3][e];
    int base = atomicAdd(&cnt[e], c0 + c1 + c2 + c3);
    woff[0][e] = base;
    woff[1][e] = base + c0;
    woff[2][e] = base + c0 + c1;
    woff[3][e] = base + c0 + c1 + c2;
  }
  __syncthreads();
  rank[2 * t] = woff[wid][e0] + r0;
  rank[2 * t + 1] = woff[wid][e1] + r1;
}

__global__ void k_offsets(const int* __restrict__ cnt, int* __restrict__ off) {
  if (threadIdx.x == 0) {
    int s = 0;
    for (int e = 0; e < NE; e++) { off[e] = s; s += cnt[e]; }
  }
}

__global__ __launch_bounds__(256) void k_scatter(const int* __restrict__ off,
                                                 const int* __restrict__ esel,
                                                 const int* __restrict__ rank,
                                                 int* __restrict__ tok_of_slot,
                                                 int* __restrict__ slot_of_tok) {
  int t = blockIdx.x * 256 + threadIdx.x;
#pragma unroll
  for (int j = 0; j < 2; j++) {
    int e = esel[2 * t + j];
    int s = off[e] + rank[2 * t + j];
    tok_of_slot[s] = t;
    slot_of_tok[2 * t + j] = s;
  }
}

// ===== 256x256-tile BK=64 grouped GEMM, derived counted-vmcnt half-tile =====
// 1 block/CU, 8 waves = 2(M:wr) x 4(N:wcn), wave tile 128x64, acc[8][4].
// LDS: A[2][2half][128][64] + B same = 128 KB. Swizzle: 16B-chunk c stored at
// c ^ (row&7) (R5-verified conflict-free); linear dest + inv-swizzled source.
// Phases per ktile split by ks: q0: m0-3*ks0 (reads a4+b0_4), q1: m0-3*ks1
// (a4+b1_4), q2: m4-7*ks0 (a4, B held), q3: m4-7*ks1 (a4, held). 16 MFMA each.
// Staging 1 half-tile/phase: q0->B1(kt+1), q1->A1(kt+1), q2->A0(kt+2),
// q3->B0(kt+2); every target region dead >=1 barrier before overwrite.
// Waits: vmcnt(6)@q0, vmcnt(8)@q2 ONLY (FIFO retire-set = exactly the halves
// needed; 4-6 phases of lead; never drains to 0). Barriers at q0/q2 only.
// FFN1=1: A = xb gathered, B = wcat group (n-frags 0,1 = W1 cols, 2,3 = W3
//         same cols -> silu lane-local), epilogue -> h (128 cols/blk)
// FFN1=0: A = h (slot rows), B = w2t, epilogue -> y (256 cols/blk)
template<int FFN1>
__global__ __launch_bounds__(512, 2) void k_ffn(const short* __restrict__ Abase,
                                                const short* __restrict__ Bbase,
                                                const int* __restrict__ cnt,
                                                const int* __restrict__ off,
                                                const int* __restrict__ tok_of_slot,
                                                short* __restrict__ outp) {
  const int e = blockIdx.y;
  const int cnt_e = cnt[e];
  const int m0 = blockIdx.z * 256;
  if (m0 >= cnt_e) return;
  const int bse = off[e];
  const int nt = blockIdx.x;
  const short* Bt = Bbase + (size_t)e * ((FFN1 ? 2048 : 1024) * 1024) + (size_t)(nt * 256) * 1024;

  __shared__ __align__(128) short Al[2][16384];  // [half][128][64] x2buf = 64 KB
  __shared__ __align__(128) short Bl[2][16384];  // 64 KB (128 KB total)

  const int tid = threadIdx.x;
  const int lane = tid & 63, wid = tid >> 6;
  const int wr = wid >> 2, wcn = wid & 3;

  // ---- staging sources: seg s = wid*2+j covers rows s*8+(lane>>3) of a half;
  //      source chunk sc = (lane&7) ^ (lane>>3) (inverse swizzle; LDS linear)
  const int sc = ((lane & 7) ^ (lane >> 3)) * 8;
  const short* srcA[2][2];  // [j][h]
  const short* srcB[2];     // [j]; half via +131072
#pragma unroll
  for (int j = 0; j < 2; j++) {
#pragma unroll
    for (int h = 0; h < 2; h++) {
      int r = h * 128 + (wid * 2 + j) * 8 + (lane >> 3);
      int row = m0 + r; if (row >= cnt_e) row = cnt_e - 1;
      long ar = FFN1 ? (long)tok_of_slot[bse + row] : (long)(bse + row);
      srcA[j][h] = Abase + ar * 1024 + sc;
    }
    srcB[j] = Bt + (size_t)((wid * 2 + j) * 8 + (lane >> 3)) * 1024 + sc;
  }

  // ---- fragment LDS byte offsets (ks0 bases; ks1 = ^64) ----
  const int chnk = ((lane >> 4) ^ (lane & 7)) * 16;
  const int aB0 = (wr * 16 + (lane & 15)) * 128 + chnk;
  const int aB1 = aB0 ^ 64;
  const int bB0 = (wcn * 16 + (lane & 15)) * 128 + chnk;
  const int bB1 = bB0 ^ 64;

  f32x4 acc[8][4];
#pragma unroll
  for (int m = 0; m < 8; m++)
#pragma unroll
    for (int n = 0; n < 4; n++) acc[m][n] = (f32x4){0.f, 0.f, 0.f, 0.f};

#define STG_A(b, h, kt) { \
    gl_lds(srcA[0][h] + (kt) * 64, &Al[b][(h) * 8192 + (wid * 2 + 0) * 512]); \
    gl_lds(srcA[1][h] + (kt) * 64, &Al[b][(h) * 8192 + (wid * 2 + 1) * 512]); }
#define STG_B(b, h, kt) { \
    gl_lds(srcB[0] + (h) * 131072 + (kt) * 64, &Bl[b][(h) * 8192 + (wid * 2 + 0) * 512]); \
    gl_lds(srcB[1] + (h) * 131072 + (kt) * 64, &Bl[b][(h) * 8192 + (wid * 2 + 1) * 512]); }

  // prologue: FIFO order matching steady schedule: A0(0),B0(0),B1(0),A1(0),A0(1),B0(1)
  STG_A(0, 0, 0); STG_B(0, 0, 0); STG_B(0, 1, 0); STG_A(0, 1, 0);
  STG_A(1, 0, 1); STG_B(1, 0, 1);

#define KTBODY(KT, BUF) { \
    const int kA = ((KT) + 1 < 16) ? (KT) + 1 : 15; \
    const int kB = ((KT) + 2 < 16) ? (KT) + 2 : 15; \
    const char* pA = (const char*)(&Al[BUF][0]); \
    const char* pB = (const char*)(&Bl[BUF][0]); \
    short8 a[4], b0[4], b1[4]; \
    /* q0: m0-3 ks0 */ \
    asm volatile("s_waitcnt vmcnt(6)" ::: "memory"); \
    __builtin_amdgcn_s_barrier(); \
    _Pragma("unroll") for (int m = 0; m < 4; m++) a[m] = *(const short8*)(pA + aB0 + m * 4096); \
    _Pragma("unroll") for (int n = 0; n < 4; n++) b0[n] = *(const short8*)(pB + bB0 + (n & 1) * 8192 + (n >> 1) * 16384); \
    STG_B(BUF ^ 1, 1, kA); \
    __builtin_amdgcn_s_setprio(1); \
    _Pragma("unroll") for (int m = 0; m < 4; m++) \
      _Pragma("unroll") for (int n = 0; n < 4; n++) \
        acc[m][n] = __builtin_amdgcn_mfma_f32_16x16x32_bf16(a[m], b0[n], acc[m][n], 0, 0, 0); \
    __builtin_amdgcn_s_setprio(0); \
    /* q1: m0-3 ks1 */ \
    _Pragma("unroll") for (int m = 0; m < 4; m++) a[m] = *(const short8*)(pA + aB1 + m * 4096); \
    _Pragma("unroll") for (int n = 0; n < 4; n++) b1[n] = *(const short8*)(pB + bB1 + (n & 1) * 8192 + (n >> 1) * 16384); \
    STG_A(BUF ^ 1, 1, kA); \
    __builtin_amdgcn_s_setprio(1); \
    _Pragma("unroll") for (int m = 0; m < 4; m++) \
      _Pragma("unroll") for (int n = 0; n < 4; n++) \
        acc[m][n] = __builtin_amdgcn_mfma_f32_16x16x32_bf16(a[m], b1[n], acc[m][n], 0, 0, 0); \
    __builtin_amdgcn_s_setprio(0); \
    /* q2: m4-7 ks0 */ \
    asm volatile("s_waitcnt vmcnt(8)" ::: "memory"); \
    __builtin_amdgcn_s_barrier(); \
    _Pragma("unroll") for (int m = 0; m < 4; m++) a[m] = *(const short8*)(pA + aB0 + 16384 + m * 4096); \
    STG_A(BUF, 0, kB); \
    __builtin_amdgcn_s_setprio(1); \
    _Pragma("unroll") for (int m = 0; m < 4; m++) \
      _Pragma("unroll") for (int n = 0; n < 4; n++) \
        acc[m + 4][n] = __builtin_amdgcn_mfma_f32_16x16x32_bf16(a[m], b0[n], acc[m + 4][n], 0, 0, 0); \
    __builtin_amdgcn_s_setprio(0); \
    /* q3: m4-7 ks1 */ \
    _Pragma("unroll") for (int m = 0; m < 4; m++) a[m] = *(const short8*)(pA + aB1 + 16384 + m * 4096); \
    STG_B(BUF, 0, kB); \
    __builtin_amdgcn_s_setprio(1); \
    _Pragma("unroll") for (int m = 0; m < 4; m++) \
      _Pragma("unroll") for (int n = 0; n < 4; n++) \
        acc[m + 4][n] = __builtin_amdgcn_mfma_f32_16x16x32_bf16(a[m], b1[n], acc[m + 4][n], 0, 0, 0); \
    __builtin_amdgcn_s_setprio(0); \
  }

  for (int kt2 = 0; kt2 < 16; kt2 += 2) {
    KTBODY(kt2, 0);
    KTBODY(kt2 + 1, 1);
  }
  asm volatile("s_waitcnt vmcnt(0)" ::: "memory");  // drain before exit

  // ---- epilogue ----
  // output row for frag m: m0 + (m>>2)*128 + (m&3)*32 + wr*16 + (lane>>4)*4 + i
  if (FFN1) {
#pragma unroll
    for (int m = 0; m < 8; m++)
#pragma unroll
      for (int n = 0; n < 2; n++) {
        f32x4 v1 = acc[m][n], v3 = acc[m][n + 2];
        int col = nt * 128 + n * 64 + wcn * 16 + (lane & 15);
#pragma unroll
        for (int i = 0; i < 4; i++) {
          int row = m0 + (m >> 2) * 128 + (m & 3) * 32 + wr * 16 + ((lane >> 4) * 4) + i;
          if (row < cnt_e) {
            float a1v = v1[i];
            float hv = (a1v / (1.f + __expf(-a1v))) * v3[i];
            outp[(size_t)(bse + row) * DE + col] = (short)f2bf(hv);
          }
        }
      }
  } else {
#pragma unroll
    for (int m = 0; m < 8; m++)
#pragma unroll
      for (int n = 0; n < 4; n++) {
        f32x4 v = acc[m][n];
        int col = nt * 256 + (n >> 1) * 128 + (n & 1) * 64 + wcn * 16 + (lane & 15);
#pragma unroll
        for (int i = 0; i < 4; i++) {
          int row = m0 + (m >> 2) * 128 + (m & 3) * 32 + wr * 16 + ((lane >> 4) * 4) + i;
          if (row < cnt_e)
            outp[(size_t)(bse + row) * DM + col] = (short)f2bf(v[i]);
        }
      }
  }
}

// ---------------- combine: out[t] = w0*y[s0] + w1*y[s1] ----------------
__global__ __launch_bounds__(256) void k_combine(const short* __restrict__ y,
                                                 const int* __restrict__ slot_of_tok,
                                                 const float* __restrict__ wgt,
                                                 float* __restrict__ out) {
  int t = blockIdx.x;
  int s0 = slot_of_tok[2 * t], s1 = slot_of_tok[2 * t + 1];
  float w0 = wgt[2 * t], w1 = wgt[2 * t + 1];
  int c = threadIdx.x * 4;
  short4v a = *(const short4v*)(y + (size_t)s0 * DM + c);
  short4v b = *(const short4v*)(y + (size_t)s1 * DM + c);
  f32x4 o;
#pragma unroll
  for (int j = 0; j < 4; j++)
    o[j] = w0 * bf2f((unsigned short)a[j]) + w1 * bf2f((unsigned short)b[j]);
  *(f32x4*)(out + (size_t)t * DM + c) = o;
}

extern "C" void kernel_launch(void* const* d_in, const int* in_sizes, int n_in,
                              void* d_out, int out_size, void* d_ws, size_t ws_size,
                              hipStream_t stream) {
  const float* x  = (const float*)d_in[0];
  const float* Wr = (const float*)d_in[1];
  const float* W1 = (const float*)d_in[2];
  const float* W2 = (const float*)d_in[3];
  const float* W3 = (const float*)d_in[4];
  float* out = (float*)d_out;
  char* ws = (char*)d_ws;

  short* xb   = (short*)(ws);                   // 16 MB
  short* wcat = (short*)(ws + 16777216);        // 32 MB (8 x 2048 x 1024 bf16)
  short* w2t  = (short*)(ws + 50331648);        // 16 MB
  short* h    = (short*)(ws + 67108864);        // 32 MB
  short* y    = (short*)(ws + 100663296);       // 32 MB
  char* meta = ws + 134217728;
  int* cnt          = (int*)(meta);
  int* off          = (int*)(meta + 256);
  int* esel         = (int*)(meta + 512);
  int* rank         = (int*)(meta + 512 + 65536);
  int* tok_of_slot  = (int*)(meta + 512 + 2 * 65536);
  int* slot_of_tok  = (int*)(meta + 512 + 3 * 65536);
  float* wgt        = (float*)(meta + 512 + 4 * 65536);

  hipMemsetAsync(cnt, 0, 32, stream);
  k_transw<<<dim3(16, 16, 24), 256, 0, stream>>>(W1, W2, W3, wcat, w2t);
  k_router<<<2048, 256, 0, stream>>>(x, Wr, xb, esel, wgt);
  k_rank<<<32, 256, 0, stream>>>(esel, cnt, rank);
  k_offsets<<<1, 64, 0, stream>>>(cnt, off);
  k_scatter<<<32, 256, 0, stream>>>(off, esel, rank, tok_of_slot, slot_of_tok);
  k_ffn<1><<<dim3(8, 8, 32), 512, 0, stream>>>(xb, wcat, cnt, off, tok_of_slot, h);
  k_ffn<0><<<dim3(4, 8, 32), 512, 0, stream>>>(h, w2t, cnt, off, tok_of_slot, y);
  k_combine<<<8192, 256, 0, stream>>>(y, slot_of_tok, wgt, out);
}

// Round 7
// 250.157 us; speedup vs baseline: 1.0468x; 1.0140x over previous
//
#include <hip/hip_runtime.h>
#include <hip/hip_bf16.h>

typedef __attribute__((ext_vector_type(8))) short short8;
typedef __attribute__((ext_vector_type(4))) short short4v;
typedef __attribute__((ext_vector_type(4))) unsigned short ushort4v;
typedef __attribute__((ext_vector_type(4))) float f32x4;

#define NTOK 8192
#define DM 1024
#define DE 1024
#define NE 8

__device__ __forceinline__ float bf2f(unsigned short u) {
  union { unsigned int i; float f; } v; v.i = ((unsigned int)u) << 16; return v.f;
}
__device__ __forceinline__ unsigned short f2bf(float f) {
  union { float f; unsigned int i; } v; v.f = f;
  unsigned int lsb = (v.i >> 16) & 1;
  v.i += 0x7fffu + lsb;  // RNE; inputs finite
  return (unsigned short)(v.i >> 16);
}
__device__ __forceinline__ void gl_lds(const short* g, short* l) {
  __builtin_amdgcn_global_load_lds((const __attribute__((address_space(1))) void*)g,
                                   (__attribute__((address_space(3))) void*)l, 16, 0, 0);
}

// ------- W fp32 [K][N] -> bf16 transposed; W1/W3 interleaved into wcat -------
// wcat[e]: 2048 rows in 128-row groups: group g rows [g*128, g*128+64) = W1^T
//          cols g*64+[0,64); rows +64 = W3^T same cols.
// w2t[e]: plain W2^T [1024][1024]
__global__ __launch_bounds__(256) void k_transw(const float* __restrict__ W1,
                                                const float* __restrict__ W2,
                                                const float* __restrict__ W3,
                                                short* __restrict__ wcat,
                                                short* __restrict__ w2t) {
  __shared__ float t[64][65];
  int mid = blockIdx.z;
  const float* src;
  if (mid < 8)       src = W1 + (size_t)mid * (DM * DE);
  else if (mid < 16) src = W3 + (size_t)(mid - 8) * (DM * DE);
  else               src = W2 + (size_t)(mid - 16) * (DE * DM);
  int tid = threadIdx.x;
  int tr = tid >> 4, tc = tid & 15;
  int kbase = blockIdx.y * 64, nbase = blockIdx.x * 64;
#pragma unroll
  for (int j = 0; j < 4; j++) {
    int kr = tr + j * 16;
    f32x4 v = *(const f32x4*)(src + (size_t)(kbase + kr) * 1024 + nbase + tc * 4);
    t[kr][tc * 4 + 0] = v[0]; t[kr][tc * 4 + 1] = v[1];
    t[kr][tc * 4 + 2] = v[2]; t[kr][tc * 4 + 3] = v[3];
  }
  __syncthreads();
#pragma unroll
  for (int j = 0; j < 4; j++) {
    int n = tr + j * 16;          // source column (0..1023 within this matrix)
    int ng = nbase + n;
    short4v o;
    o[0] = (short)f2bf(t[tc * 4 + 0][n]);
    o[1] = (short)f2bf(t[tc * 4 + 1][n]);
    o[2] = (short)f2bf(t[tc * 4 + 2][n]);
    o[3] = (short)f2bf(t[tc * 4 + 3][n]);
    size_t dsto;
    if (mid < 16) {
      int e = mid & 7, p = mid >> 3;
      int row_out = ((ng >> 6) * 128) + p * 64 + (ng & 63);
      dsto = (size_t)e * (2048 * 1024) + (size_t)row_out * 1024 + kbase + tc * 4;
      *(short4v*)(wcat + dsto) = o;
    } else {
      int e = mid - 16;
      dsto = (size_t)e * (1024 * 1024) + (size_t)ng * 1024 + kbase + tc * 4;
      *(short4v*)(w2t + dsto) = o;
    }
  }
}

// ------- router: fp32 logits, softmax-top2, fused x->bf16 conversion -------
__global__ __launch_bounds__(256) void k_router(const float* __restrict__ x,
                                                const float* __restrict__ Wr,
                                                short* __restrict__ xb,
                                                int* __restrict__ esel,
                                                float* __restrict__ wgt) {
  int wid = threadIdx.x >> 6, lane = threadIdx.x & 63;
  int t = blockIdx.x * 4 + wid;
  const float* xr = x + (size_t)t * DM;
  float acc[8];
#pragma unroll
  for (int e = 0; e < 8; e++) acc[e] = 0.f;
#pragma unroll
  for (int i = 0; i < 4; i++) {
    int kb = (i * 64 + lane) * 4;
    f32x4 v = *(const f32x4*)(xr + kb);
    ushort4v ob;
#pragma unroll
    for (int j = 0; j < 4; j++) {
      f32x4 w0 = *(const f32x4*)(Wr + (size_t)(kb + j) * 8);
      f32x4 w1 = *(const f32x4*)(Wr + (size_t)(kb + j) * 8 + 4);
      float xv = v[j];
      ob[j] = f2bf(xv);
      acc[0] += xv * w0[0]; acc[1] += xv * w0[1];
      acc[2] += xv * w0[2]; acc[3] += xv * w0[3];
      acc[4] += xv * w1[0]; acc[5] += xv * w1[1];
      acc[6] += xv * w1[2]; acc[7] += xv * w1[3];
    }
    *(ushort4v*)(xb + (size_t)t * DM + kb) = ob;
  }
#pragma unroll
  for (int off = 32; off; off >>= 1)
#pragma unroll
    for (int e = 0; e < 8; e++) acc[e] += __shfl_xor(acc[e], off);
  float m0 = -1e30f, m1 = -1e30f; int e0 = 0, e1 = 0;
#pragma unroll
  for (int e = 0; e < 8; e++) {
    float v = acc[e];
    if (v > m0) { m1 = m0; e1 = e0; m0 = v; e0 = e; }
    else if (v > m1) { m1 = v; e1 = e; }
  }
  float p = __expf(m1 - m0);
  if (lane == 0) {
    esel[2 * t] = e0; esel[2 * t + 1] = e1;
    wgt[2 * t] = 1.f / (1.f + p); wgt[2 * t + 1] = p / (1.f + p);
  }
}

// ---- ranks via wave ballots + per-block aggregated atomics ----
__global__ __launch_bounds__(256) void k_rank(const int* __restrict__ esel,
                                              int* __restrict__ cnt,
                                              int* __restrict__ rank) {
  __shared__ int wcnt[4][8];
  __shared__ int woff[4][8];
  int tid = threadIdx.x;
  int lane = tid & 63, wid = tid >> 6;
  int t = blockIdx.x * 256 + tid;
  int e0 = esel[2 * t], e1 = esel[2 * t + 1];
  unsigned long long lt = (lane == 0) ? 0ull : ((~0ull) >> (64 - lane));
  int r0 = 0, r1 = 0;
#pragma unroll
  for (int e = 0; e < 8; e++) {
    unsigned long long m0 = __ballot(e0 == e);
    unsigned long long m1 = __ballot(e1 == e);
    int c0 = __popcll(m0);
    if (e0 == e) r0 = __popcll(m0 & lt);
    if (e1 == e) r1 = c0 + __popcll(m1 & lt);
    if (lane == 0) wcnt[wid][e] = c0 + __popcll(m1);
  }
  __syncthreads();
  if (tid < 8) {
    int e = tid;
    int c0 = wcnt[0][e], c1 = wcnt[1][e], c2 = wcnt[2][e], c3 = wcnt[3][e];
    int base = atomicAdd(&cnt[e], c0 + c1 + c2 + c3);
    woff[0][e] = base;
    woff[1][e] = base + c0;
    woff[2][e] = base + c0 + c1;
    woff[3][e] = base + c0 + c1 + c2;
  }
  __syncthreads();
  rank[2 * t] = woff[wid][e0] + r0;
  rank[2 * t + 1] = woff[wid][e1] + r1;
}

__global__ void k_offsets(const int* __restrict__ cnt, int* __restrict__ off) {
  if (threadIdx.x == 0) {
    int s = 0;
    for (int e = 0; e < NE; e++) { off[e] = s; s += cnt[e]; }
  }
}

__global__ __launch_bounds__(256) void k_scatter(const int* __restrict__ off,
                                                 const int* __restrict__ esel,
                                                 const int* __restrict__ rank,
                                                 int* __restrict__ tok_of_slot,
                                                 int* __restrict__ slot_of_tok) {
  int t = blockIdx.x * 256 + threadIdx.x;
#pragma unroll
  for (int j = 0; j < 2; j++) {
    int e = esel[2 * t + j];
    int s = off[e] + rank[2 * t + j];
    tok_of_slot[s] = t;
    slot_of_tok[2 * t + j] = s;
  }
}

// ===== 256x128-tile BK=32 grouped GEMM, 4-wave blocks, 128x64 wave tiles =====
// Why this shape (R1..R6 synthesis): LDS-read bytes/MFMA = 32768(Mw+Nw)/(Mw*Nw)
//   64x64 wave tile (R1) -> 1024 B/instr -> LDS caps util at ~61%
//   128x64 (R5/R6)       ->  768 B/instr -> cap ~81%, but 1 block/CU serialized
// 4-wave (256-thr) blocks give BOTH: 2 blocks/CU (independent barrier groups
// overlap each other's stalls, the R0->R1 lever) AND 128x64 wave tiles
// (2 waves/SIMD -> 256-reg budget: acc[8][4]=128 + ~90 arch fits).
// LDS: 3-ring x (A 16KB + B 8KB) = 72 KB -> 2 blocks = 144 <= 160.
// Single barrier per tile + counted vmcnt(6) (2 tiles in flight, never 0 in
// loop): slot written at tile t was last read at t-1, ordered by t-1's barrier.
// FFN1=1: A = xb gathered via tok_of_slot, B = wcat (128-row group = 64 W1 +
//         64 W3 col pairs), epilogue silu(a1)*a3 -> h (64 cols/blk)
// FFN1=0: A = h (slot rows), B = w2t, epilogue -> y (128 cols/blk)
template<int FFN1>
__global__ __launch_bounds__(256, 2) void k_ffn(const short* __restrict__ Abase,
                                                const short* __restrict__ Bbase,
                                                const int* __restrict__ cnt,
                                                const int* __restrict__ off,
                                                const int* __restrict__ tok_of_slot,
                                                short* __restrict__ outp) {
  const int e = blockIdx.y;
  const int cnt_e = cnt[e];
  const int m0 = blockIdx.z * 256;
  if (m0 >= cnt_e) return;
  const int bse = off[e];
  const int nt = blockIdx.x;
  const short* Bt = Bbase + (size_t)e * ((FFN1 ? 2048 : 1024) * 1024) + (size_t)(nt * 128) * 1024;

  // k-tile: A 256x32 bf16 = 16 KB (8192 shorts), B 128x32 = 8 KB (4096)
  __shared__ __align__(128) short Al[3][8192];  // 48 KB
  __shared__ __align__(128) short Bl[3][4096];  // 24 KB (72 KB total)

  const int tid = threadIdx.x;
  const int lane = tid & 63, wid = tid >> 6;   // 4 waves
  const int wr = wid >> 1, wcn = wid & 1;      // 2M x 2N, wave tile 128x64

  // staging: chunk ch = tid + i*256; row r = ch>>2; src col-chunk
  // c = (ch&3) ^ ((r>>1)&3)  (inverse-swizzled source, linear LDS dest)
  const short* srcA[4]; const short* srcB[2];
#pragma unroll
  for (int i = 0; i < 4; i++) {
    int ch = tid + i * 256;
    int r = ch >> 2, c = (ch & 3) ^ ((r >> 1) & 3);
    int row = m0 + r; if (row >= cnt_e) row = cnt_e - 1;
    long ar = FFN1 ? (long)tok_of_slot[bse + row] : (long)(bse + row);
    srcA[i] = Abase + ar * 1024 + c * 8;
    if (i < 2) srcB[i] = Bt + (size_t)r * 1024 + c * 8;   // r < 128 for ch < 512
  }

  // fragment LDS byte offsets (proven 0-conflict read pattern)
  int aoff[8], boff[4];
#pragma unroll
  for (int m = 0; m < 8; m++) {
    int r = wr * 128 + m * 16 + (lane & 15);
    aoff[m] = (r * 4 + ((lane >> 4) ^ ((r >> 1) & 3))) * 16;
  }
#pragma unroll
  for (int n = 0; n < 4; n++) {
    int rb = FFN1 ? (wcn * 32 + (n & 1) * 16 + (n >> 1) * 64 + (lane & 15))
                  : (wcn * 64 + n * 16 + (lane & 15));
    boff[n] = (rb * 4 + ((lane >> 4) ^ ((rb >> 1) & 3))) * 16;
  }

  f32x4 acc[8][4];
#pragma unroll
  for (int m = 0; m < 8; m++)
#pragma unroll
    for (int n = 0; n < 4; n++) acc[m][n] = (f32x4){0.f, 0.f, 0.f, 0.f};

#define STG_A(b, kt) { gl_lds(srcA[0] + (kt) * 32, &Al[b][(tid + 0) * 8]); \
                       gl_lds(srcA[1] + (kt) * 32, &Al[b][(tid + 256) * 8]); \
                       gl_lds(srcA[2] + (kt) * 32, &Al[b][(tid + 512) * 8]); \
                       gl_lds(srcA[3] + (kt) * 32, &Al[b][(tid + 768) * 8]); }
#define STG_B(b, kt) { gl_lds(srcB[0] + (kt) * 32, &Bl[b][(tid + 0) * 8]); \
                       gl_lds(srcB[1] + (kt) * 32, &Bl[b][(tid + 256) * 8]); }

  // prologue: tiles 0,1 issued (6 ops each); wait tile 0 (tile 1 in flight)
  STG_A(0, 0); STG_B(0, 0);
  STG_A(1, 1); STG_B(1, 1);
  asm volatile("s_waitcnt vmcnt(6)" ::: "memory");
  __builtin_amdgcn_s_barrier();

  int cur = 0, nxt = 2;
  for (int t = 0; t < 32; ++t) {
    int ktn = (t + 2 < 32) ? (t + 2) : 31;  // clamped dup-stage: benign
    const char* Ab = (const char*)Al[cur];
    const char* Bb = (const char*)Bl[cur];
    short8 a[8], b[4];
#pragma unroll
    for (int m = 0; m < 8; m++) a[m] = *(const short8*)(Ab + aoff[m]);
#pragma unroll
    for (int n = 0; n < 4; n++) b[n] = *(const short8*)(Bb + boff[n]);
    STG_A(nxt, ktn); STG_B(nxt, ktn);
    __builtin_amdgcn_s_setprio(1);
#pragma unroll
    for (int m = 0; m < 8; m++)
#pragma unroll
      for (int n = 0; n < 4; n++)
        acc[m][n] = __builtin_amdgcn_mfma_f32_16x16x32_bf16(a[m], b[n], acc[m][n], 0, 0, 0);
    __builtin_amdgcn_s_setprio(0);
    asm volatile("s_waitcnt vmcnt(6)" ::: "memory");  // tile t+1 landed; t+2 in flight
    __builtin_amdgcn_s_barrier();
    cur = (cur == 2) ? 0 : cur + 1;
    nxt = (nxt == 2) ? 0 : nxt + 1;
  }
  asm volatile("s_waitcnt vmcnt(0)" ::: "memory");  // drain before LDS dealloc

  // ---- epilogue ----
  if (FFN1) {
#pragma unroll
    for (int m = 0; m < 8; m++)
#pragma unroll
      for (int cc = 0; cc < 2; cc++) {
        f32x4 v1 = acc[m][cc], v3 = acc[m][cc + 2];
        int col = nt * 64 + wcn * 32 + cc * 16 + (lane & 15);
#pragma unroll
        for (int i = 0; i < 4; i++) {
          int row = m0 + wr * 128 + m * 16 + ((lane >> 4) * 4) + i;
          if (row < cnt_e) {
            float a1v = v1[i];
            float hv = (a1v / (1.f + __expf(-a1v))) * v3[i];
            outp[(size_t)(bse + row) * DE + col] = (short)f2bf(hv);
          }
        }
      }
  } else {
#pragma unroll
    for (int m = 0; m < 8; m++)
#pragma unroll
      for (int n = 0; n < 4; n++) {
        f32x4 v = acc[m][n];
        int col = nt * 128 + wcn * 64 + n * 16 + (lane & 15);
#pragma unroll
        for (int i = 0; i < 4; i++) {
          int row = m0 + wr * 128 + m * 16 + ((lane >> 4) * 4) + i;
          if (row < cnt_e)
            outp[(size_t)(bse + row) * DM + col] = (short)f2bf(v[i]);
        }
      }
  }
}

// ---------------- combine: out[t] = w0*y[s0] + w1*y[s1] ----------------
__global__ __launch_bounds__(256) void k_combine(const short* __restrict__ y,
                                                 const int* __restrict__ slot_of_tok,
                                                 const float* __restrict__ wgt,
                                                 float* __restrict__ out) {
  int t = blockIdx.x;
  int s0 = slot_of_tok[2 * t], s1 = slot_of_tok[2 * t + 1];
  float w0 = wgt[2 * t], w1 = wgt[2 * t + 1];
  int c = threadIdx.x * 4;
  short4v a = *(const short4v*)(y + (size_t)s0 * DM + c);
  short4v b = *(const short4v*)(y + (size_t)s1 * DM + c);
  f32x4 o;
#pragma unroll
  for (int j = 0; j < 4; j++)
    o[j] = w0 * bf2f((unsigned short)a[j]) + w1 * bf2f((unsigned short)b[j]);
  *(f32x4*)(out + (size_t)t * DM + c) = o;
}

extern "C" void kernel_launch(void* const* d_in, const int* in_sizes, int n_in,
                              void* d_out, int out_size, void* d_ws, size_t ws_size,
                              hipStream_t stream) {
  const float* x  = (const float*)d_in[0];
  const float* Wr = (const float*)d_in[1];
  const float* W1 = (const float*)d_in[2];
  const float* W2 = (const float*)d_in[3];
  const float* W3 = (const float*)d_in[4];
  float* out = (float*)d_out;
  char* ws = (char*)d_ws;

  short* xb   = (short*)(ws);                   // 16 MB
  short* wcat = (short*)(ws + 16777216);        // 32 MB (8 x 2048 x 1024 bf16)
  short* w2t  = (short*)(ws + 50331648);        // 16 MB
  short* h    = (short*)(ws + 67108864);        // 32 MB
  short* y    = (short*)(ws + 100663296);       // 32 MB
  char* meta = ws + 134217728;
  int* cnt          = (int*)(meta);
  int* off          = (int*)(meta + 256);
  int* esel         = (int*)(meta + 512);
  int* rank         = (int*)(meta + 512 + 65536);
  int* tok_of_slot  = (int*)(meta + 512 + 2 * 65536);
  int* slot_of_tok  = (int*)(meta + 512 + 3 * 65536);
  float* wgt        = (float*)(meta + 512 + 4 * 65536);

  hipMemsetAsync(cnt, 0, 32, stream);
  k_transw<<<dim3(16, 16, 24), 256, 0, stream>>>(W1, W2, W3, wcat, w2t);
  k_router<<<2048, 256, 0, stream>>>(x, Wr, xb, esel, wgt);
  k_rank<<<32, 256, 0, stream>>>(esel, cnt, rank);
  k_offsets<<<1, 64, 0, stream>>>(cnt, off);
  k_scatter<<<32, 256, 0, stream>>>(off, esel, rank, tok_of_slot, slot_of_tok);
  k_ffn<1><<<dim3(16, 8, 32), 256, 0, stream>>>(xb, wcat, cnt, off, tok_of_slot, h);
  k_ffn<0><<<dim3(8, 8, 32), 256, 0, stream>>>(h, w2t, cnt, off, tok_of_slot, y);
  k_combine<<<8192, 256, 0, stream>>>(y, slot_of_tok, wgt, out);
}

// Round 8
// 243.497 us; speedup vs baseline: 1.0754x; 1.0274x over previous
//
#include <hip/hip_runtime.h>
#include <hip/hip_bf16.h>

typedef __attribute__((ext_vector_type(8))) short short8;
typedef __attribute__((ext_vector_type(4))) short short4v;
typedef __attribute__((ext_vector_type(4))) unsigned short ushort4v;
typedef __attribute__((ext_vector_type(4))) float f32x4;

#define NTOK 8192
#define DM 1024
#define DE 1024
#define NE 8

__device__ __forceinline__ float bf2f(unsigned short u) {
  union { unsigned int i; float f; } v; v.i = ((unsigned int)u) << 16; return v.f;
}
__device__ __forceinline__ unsigned short f2bf(float f) {
  union { float f; unsigned int i; } v; v.f = f;
  unsigned int lsb = (v.i >> 16) & 1;
  v.i += 0x7fffu + lsb;  // RNE; inputs finite
  return (unsigned short)(v.i >> 16);
}
__device__ __forceinline__ void gl_lds(const short* g, short* l) {
  __builtin_amdgcn_global_load_lds((const __attribute__((address_space(1))) void*)g,
                                   (__attribute__((address_space(3))) void*)l, 16, 0, 0);
}

// ------- W fp32 [K][N] -> bf16 transposed; W1/W3 interleaved into wcat -------
// wcat[e]: 2048 rows in 128-row groups: group g rows [g*128, g*128+64) = W1^T
//          cols g*64+[0,64); rows +64 = W3^T same cols.
// w2t[e]: plain W2^T [1024][1024]
__global__ __launch_bounds__(256) void k_transw(const float* __restrict__ W1,
                                                const float* __restrict__ W2,
                                                const float* __restrict__ W3,
                                                short* __restrict__ wcat,
                                                short* __restrict__ w2t) {
  __shared__ float t[64][65];
  int mid = blockIdx.z;
  const float* src;
  if (mid < 8)       src = W1 + (size_t)mid * (DM * DE);
  else if (mid < 16) src = W3 + (size_t)(mid - 8) * (DM * DE);
  else               src = W2 + (size_t)(mid - 16) * (DE * DM);
  int tid = threadIdx.x;
  int tr = tid >> 4, tc = tid & 15;
  int kbase = blockIdx.y * 64, nbase = blockIdx.x * 64;
#pragma unroll
  for (int j = 0; j < 4; j++) {
    int kr = tr + j * 16;
    f32x4 v = *(const f32x4*)(src + (size_t)(kbase + kr) * 1024 + nbase + tc * 4);
    t[kr][tc * 4 + 0] = v[0]; t[kr][tc * 4 + 1] = v[1];
    t[kr][tc * 4 + 2] = v[2]; t[kr][tc * 4 + 3] = v[3];
  }
  __syncthreads();
#pragma unroll
  for (int j = 0; j < 4; j++) {
    int n = tr + j * 16;          // source column (0..1023 within this matrix)
    int ng = nbase + n;
    short4v o;
    o[0] = (short)f2bf(t[tc * 4 + 0][n]);
    o[1] = (short)f2bf(t[tc * 4 + 1][n]);
    o[2] = (short)f2bf(t[tc * 4 + 2][n]);
    o[3] = (short)f2bf(t[tc * 4 + 3][n]);
    size_t dsto;
    if (mid < 16) {
      int e = mid & 7, p = mid >> 3;
      int row_out = ((ng >> 6) * 128) + p * 64 + (ng & 63);
      dsto = (size_t)e * (2048 * 1024) + (size_t)row_out * 1024 + kbase + tc * 4;
      *(short4v*)(wcat + dsto) = o;
    } else {
      int e = mid - 16;
      dsto = (size_t)e * (1024 * 1024) + (size_t)ng * 1024 + kbase + tc * 4;
      *(short4v*)(w2t + dsto) = o;
    }
  }
}

// ------- router: fp32 logits, softmax-top2, fused x->bf16 conversion -------
__global__ __launch_bounds__(256) void k_router(const float* __restrict__ x,
                                                const float* __restrict__ Wr,
                                                short* __restrict__ xb,
                                                int* __restrict__ esel,
                                                float* __restrict__ wgt) {
  int wid = threadIdx.x >> 6, lane = threadIdx.x & 63;
  int t = blockIdx.x * 4 + wid;
  const float* xr = x + (size_t)t * DM;
  float acc[8];
#pragma unroll
  for (int e = 0; e < 8; e++) acc[e] = 0.f;
#pragma unroll
  for (int i = 0; i < 4; i++) {
    int kb = (i * 64 + lane) * 4;
    f32x4 v = *(const f32x4*)(xr + kb);
    ushort4v ob;
#pragma unroll
    for (int j = 0; j < 4; j++) {
      f32x4 w0 = *(const f32x4*)(Wr + (size_t)(kb + j) * 8);
      f32x4 w1 = *(const f32x4*)(Wr + (size_t)(kb + j) * 8 + 4);
      float xv = v[j];
      ob[j] = f2bf(xv);
      acc[0] += xv * w0[0]; acc[1] += xv * w0[1];
      acc[2] += xv * w0[2]; acc[3] += xv * w0[3];
      acc[4] += xv * w1[0]; acc[5] += xv * w1[1];
      acc[6] += xv * w1[2]; acc[7] += xv * w1[3];
    }
    *(ushort4v*)(xb + (size_t)t * DM + kb) = ob;
  }
#pragma unroll
  for (int off = 32; off; off >>= 1)
#pragma unroll
    for (int e = 0; e < 8; e++) acc[e] += __shfl_xor(acc[e], off);
  float m0 = -1e30f, m1 = -1e30f; int e0 = 0, e1 = 0;
#pragma unroll
  for (int e = 0; e < 8; e++) {
    float v = acc[e];
    if (v > m0) { m1 = m0; e1 = e0; m0 = v; e0 = e; }
    else if (v > m1) { m1 = v; e1 = e; }
  }
  float p = __expf(m1 - m0);
  if (lane == 0) {
    esel[2 * t] = e0; esel[2 * t + 1] = e1;
    wgt[2 * t] = 1.f / (1.f + p); wgt[2 * t + 1] = p / (1.f + p);
  }
}

// ---- ranks via wave ballots + per-block aggregated atomics ----
__global__ __launch_bounds__(256) void k_rank(const int* __restrict__ esel,
                                              int* __restrict__ cnt,
                                              int* __restrict__ rank) {
  __shared__ int wcnt[4][8];
  __shared__ int woff[4][8];
  int tid = threadIdx.x;
  int lane = tid & 63, wid = tid >> 6;
  int t = blockIdx.x * 256 + tid;
  int e0 = esel[2 * t], e1 = esel[2 * t + 1];
  unsigned long long lt = (lane == 0) ? 0ull : ((~0ull) >> (64 - lane));
  int r0 = 0, r1 = 0;
#pragma unroll
  for (int e = 0; e < 8; e++) {
    unsigned long long m0 = __ballot(e0 == e);
    unsigned long long m1 = __ballot(e1 == e);
    int c0 = __popcll(m0);
    if (e0 == e) r0 = __popcll(m0 & lt);
    if (e1 == e) r1 = c0 + __popcll(m1 & lt);
    if (lane == 0) wcnt[wid][e] = c0 + __popcll(m1);
  }
  __syncthreads();
  if (tid < 8) {
    int e = tid;
    int c0 = wcnt[0][e], c1 = wcnt[1][e], c2 = wcnt[2][e], c3 = wcnt[3][e];
    int base = atomicAdd(&cnt[e], c0 + c1 + c2 + c3);
    woff[0][e] = base;
    woff[1][e] = base + c0;
    woff[2][e] = base + c0 + c1;
    woff[3][e] = base + c0 + c1 + c2;
  }
  __syncthreads();
  rank[2 * t] = woff[wid][e0] + r0;
  rank[2 * t + 1] = woff[wid][e1] + r1;
}

__global__ void k_offsets(const int* __restrict__ cnt, int* __restrict__ off) {
  if (threadIdx.x == 0) {
    int s = 0;
    for (int e = 0; e < NE; e++) { off[e] = s; s += cnt[e]; }
  }
}

__global__ __launch_bounds__(256) void k_scatter(const int* __restrict__ off,
                                                 const int* __restrict__ esel,
                                                 const int* __restrict__ rank,
                                                 int* __restrict__ tok_of_slot,
                                                 int* __restrict__ slot_of_tok) {
  int t = blockIdx.x * 256 + threadIdx.x;
#pragma unroll
  for (int j = 0; j < 2; j++) {
    int e = esel[2 * t + j];
    int s = off[e] + rank[2 * t + j];
    tok_of_slot[s] = t;
    slot_of_tok[2 * t + j] = s;
  }
}

// ===== 256x128-tile BK=32 grouped GEMM, 4-wave blocks, 128x64 wave tiles =====
// Inner loop IDENTICAL to R7 (proven 0-conflict reads, counted vmcnt(6),
// single barrier/tile, 2 blocks/CU). ONE change: balanced (e,mt)-group -> XCD
// mapping. HW assigns block b to XCD b%8. Flat grid:
//   xcd = b&7; j = b>>3; nt = j&(NT-1); G = xcd + 8*(j>>log2NT); e=G>>5; mt=G&31
// -> all NT nt-siblings of a group (same A-panel: 256 rows x 2KB = 512 KB)
//    run back-to-back on ONE XCD: panel fetched once into its L2, rest hit.
//    A re-read traffic from L3/HBM drops 16x (FFN1) / 8x (FFN2).
// -> balance: for cnt_e ~2048, active mt per (xcd,e) = 1 -> per-XCD work equal
//    regardless of routing skew (avoids the R3 imbalance failure).
// -> consecutive groups on an XCD share e -> B-panels also L2-reused.
// FFN1=1: A = xb gathered via tok_of_slot, B = wcat (128-row group = 64 W1 +
//         64 W3 col pairs), epilogue silu(a1)*a3 -> h (64 cols/blk)
// FFN1=0: A = h (slot rows), B = w2t, epilogue -> y (128 cols/blk)
template<int FFN1>
__global__ __launch_bounds__(256, 2) void k_ffn(const short* __restrict__ Abase,
                                                const short* __restrict__ Bbase,
                                                const int* __restrict__ cnt,
                                                const int* __restrict__ off,
                                                const int* __restrict__ tok_of_slot,
                                                short* __restrict__ outp) {
  const int NT = FFN1 ? 16 : 8;
  const int b = blockIdx.x;
  const int xcd = b & 7;
  const int j = b >> 3;
  const int nt = j & (NT - 1);
  const int Gq = j >> (FFN1 ? 4 : 3);
  const int G = xcd + 8 * Gq;          // 0..255 group id
  const int e = G >> 5;
  const int mt = G & 31;

  const int cnt_e = cnt[e];
  const int m0 = mt * 256;
  if (m0 >= cnt_e) return;
  const int bse = off[e];
  const short* Bt = Bbase + (size_t)e * ((FFN1 ? 2048 : 1024) * 1024) + (size_t)(nt * 128) * 1024;

  // k-tile: A 256x32 bf16 = 16 KB (8192 shorts), B 128x32 = 8 KB (4096)
  __shared__ __align__(128) short Al[3][8192];  // 48 KB
  __shared__ __align__(128) short Bl[3][4096];  // 24 KB (72 KB total)

  const int tid = threadIdx.x;
  const int lane = tid & 63, wid = tid >> 6;   // 4 waves
  const int wr = wid >> 1, wcn = wid & 1;      // 2M x 2N, wave tile 128x64

  // staging: chunk ch = tid + i*256; row r = ch>>2; src col-chunk
  // c = (ch&3) ^ ((r>>1)&3)  (inverse-swizzled source, linear LDS dest)
  const short* srcA[4]; const short* srcB[2];
#pragma unroll
  for (int i = 0; i < 4; i++) {
    int ch = tid + i * 256;
    int r = ch >> 2, c = (ch & 3) ^ ((r >> 1) & 3);
    int row = m0 + r; if (row >= cnt_e) row = cnt_e - 1;
    long ar = FFN1 ? (long)tok_of_slot[bse + row] : (long)(bse + row);
    srcA[i] = Abase + ar * 1024 + c * 8;
    if (i < 2) srcB[i] = Bt + (size_t)r * 1024 + c * 8;   // r < 128 for ch < 512
  }

  // fragment LDS byte offsets (proven 0-conflict read pattern)
  int aoff[8], boff[4];
#pragma unroll
  for (int m = 0; m < 8; m++) {
    int r = wr * 128 + m * 16 + (lane & 15);
    aoff[m] = (r * 4 + ((lane >> 4) ^ ((r >> 1) & 3))) * 16;
  }
#pragma unroll
  for (int n = 0; n < 4; n++) {
    int rb = FFN1 ? (wcn * 32 + (n & 1) * 16 + (n >> 1) * 64 + (lane & 15))
                  : (wcn * 64 + n * 16 + (lane & 15));
    boff[n] = (rb * 4 + ((lane >> 4) ^ ((rb >> 1) & 3))) * 16;
  }

  f32x4 acc[8][4];
#pragma unroll
  for (int m = 0; m < 8; m++)
#pragma unroll
    for (int n = 0; n < 4; n++) acc[m][n] = (f32x4){0.f, 0.f, 0.f, 0.f};

#define STG_A(bb, kt) { gl_lds(srcA[0] + (kt) * 32, &Al[bb][(tid + 0) * 8]); \
                        gl_lds(srcA[1] + (kt) * 32, &Al[bb][(tid + 256) * 8]); \
                        gl_lds(srcA[2] + (kt) * 32, &Al[bb][(tid + 512) * 8]); \
                        gl_lds(srcA[3] + (kt) * 32, &Al[bb][(tid + 768) * 8]); }
#define STG_B(bb, kt) { gl_lds(srcB[0] + (kt) * 32, &Bl[bb][(tid + 0) * 8]); \
                        gl_lds(srcB[1] + (kt) * 32, &Bl[bb][(tid + 256) * 8]); }

  // prologue: tiles 0,1 issued (6 ops each); wait tile 0 (tile 1 in flight)
  STG_A(0, 0); STG_B(0, 0);
  STG_A(1, 1); STG_B(1, 1);
  asm volatile("s_waitcnt vmcnt(6)" ::: "memory");
  __builtin_amdgcn_s_barrier();

  int cur = 0, nxt = 2;
  for (int t = 0; t < 32; ++t) {
    int ktn = (t + 2 < 32) ? (t + 2) : 31;  // clamped dup-stage: benign
    const char* Ab = (const char*)Al[cur];
    const char* Bb = (const char*)Bl[cur];
    short8 a[8], bfr[4];
#pragma unroll
    for (int m = 0; m < 8; m++) a[m] = *(const short8*)(Ab + aoff[m]);
#pragma unroll
    for (int n = 0; n < 4; n++) bfr[n] = *(const short8*)(Bb + boff[n]);
    STG_A(nxt, ktn); STG_B(nxt, ktn);
    __builtin_amdgcn_s_setprio(1);
#pragma unroll
    for (int m = 0; m < 8; m++)
#pragma unroll
      for (int n = 0; n < 4; n++)
        acc[m][n] = __builtin_amdgcn_mfma_f32_16x16x32_bf16(a[m], bfr[n], acc[m][n], 0, 0, 0);
    __builtin_amdgcn_s_setprio(0);
    asm volatile("s_waitcnt vmcnt(6)" ::: "memory");  // tile t+1 landed; t+2 in flight
    __builtin_amdgcn_s_barrier();
    cur = (cur == 2) ? 0 : cur + 1;
    nxt = (nxt == 2) ? 0 : nxt + 1;
  }
  asm volatile("s_waitcnt vmcnt(0)" ::: "memory");  // drain before LDS dealloc

  // ---- epilogue ----
  if (FFN1) {
#pragma unroll
    for (int m = 0; m < 8; m++)
#pragma unroll
      for (int cc = 0; cc < 2; cc++) {
        f32x4 v1 = acc[m][cc], v3 = acc[m][cc + 2];
        int col = nt * 64 + wcn * 32 + cc * 16 + (lane & 15);
#pragma unroll
        for (int i = 0; i < 4; i++) {
          int row = m0 + wr * 128 + m * 16 + ((lane >> 4) * 4) + i;
          if (row < cnt_e) {
            float a1v = v1[i];
            float hv = (a1v / (1.f + __expf(-a1v))) * v3[i];
            outp[(size_t)(bse + row) * DE + col] = (short)f2bf(hv);
          }
        }
      }
  } else {
#pragma unroll
    for (int m = 0; m < 8; m++)
#pragma unroll
      for (int n = 0; n < 4; n++) {
        f32x4 v = acc[m][n];
        int col = nt * 128 + wcn * 64 + n * 16 + (lane & 15);
#pragma unroll
        for (int i = 0; i < 4; i++) {
          int row = m0 + wr * 128 + m * 16 + ((lane >> 4) * 4) + i;
          if (row < cnt_e)
            outp[(size_t)(bse + row) * DM + col] = (short)f2bf(v[i]);
        }
      }
  }
}

// ---------------- combine: out[t] = w0*y[s0] + w1*y[s1] ----------------
__global__ __launch_bounds__(256) void k_combine(const short* __restrict__ y,
                                                 const int* __restrict__ slot_of_tok,
                                                 const float* __restrict__ wgt,
                                                 float* __restrict__ out) {
  int t = blockIdx.x;
  int s0 = slot_of_tok[2 * t], s1 = slot_of_tok[2 * t + 1];
  float w0 = wgt[2 * t], w1 = wgt[2 * t + 1];
  int c = threadIdx.x * 4;
  short4v a = *(const short4v*)(y + (size_t)s0 * DM + c);
  short4v b = *(const short4v*)(y + (size_t)s1 * DM + c);
  f32x4 o;
#pragma unroll
  for (int j = 0; j < 4; j++)
    o[j] = w0 * bf2f((unsigned short)a[j]) + w1 * bf2f((unsigned short)b[j]);
  *(f32x4*)(out + (size_t)t * DM + c) = o;
}

extern "C" void kernel_launch(void* const* d_in, const int* in_sizes, int n_in,
                              void* d_out, int out_size, void* d_ws, size_t ws_size,
                              hipStream_t stream) {
  const float* x  = (const float*)d_in[0];
  const float* Wr = (const float*)d_in[1];
  const float* W1 = (const float*)d_in[2];
  const float* W2 = (const float*)d_in[3];
  const float* W3 = (const float*)d_in[4];
  float* out = (float*)d_out;
  char* ws = (char*)d_ws;

  short* xb   = (short*)(ws);                   // 16 MB
  short* wcat = (short*)(ws + 16777216);        // 32 MB (8 x 2048 x 1024 bf16)
  short* w2t  = (short*)(ws + 50331648);        // 16 MB
  short* h    = (short*)(ws + 67108864);        // 32 MB
  short* y    = (short*)(ws + 100663296);       // 32 MB
  char* meta = ws + 134217728;
  int* cnt          = (int*)(meta);
  int* off          = (int*)(meta + 256);
  int* esel         = (int*)(meta + 512);
  int* rank         = (int*)(meta + 512 + 65536);
  int* tok_of_slot  = (int*)(meta + 512 + 2 * 65536);
  int* slot_of_tok  = (int*)(meta + 512 + 3 * 65536);
  float* wgt        = (float*)(meta + 512 + 4 * 65536);

  hipMemsetAsync(cnt, 0, 32, stream);
  k_transw<<<dim3(16, 16, 24), 256, 0, stream>>>(W1, W2, W3, wcat, w2t);
  k_router<<<2048, 256, 0, stream>>>(x, Wr, xb, esel, wgt);
  k_rank<<<32, 256, 0, stream>>>(esel, cnt, rank);
  k_offsets<<<1, 64, 0, stream>>>(cnt, off);
  k_scatter<<<32, 256, 0, stream>>>(off, esel, rank, tok_of_slot, slot_of_tok);
  k_ffn<1><<<dim3(4096), 256, 0, stream>>>(xb, wcat, cnt, off, tok_of_slot, h);
  k_ffn<0><<<dim3(2048), 256, 0, stream>>>(h, w2t, cnt, off, tok_of_slot, y);
  k_combine<<<8192, 256, 0, stream>>>(y, slot_of_tok, wgt, out);
}